// Round 7
// baseline (384.299 us; speedup 1.0000x reference)
//
#include <hip/hip_runtime.h>
#include <math.h>
#include <stdint.h>

#define M_ROWS 8192
#define N_COLS 16384
#define K_DIM  256
#define NTILE  (N_COLS / 128)   // 128 col tiles
#define CHUNK  2048             // fallback path only
#define NCHUNK 4

typedef _Float16 half8  __attribute__((ext_vector_type(8)));
typedef _Float16 half4v __attribute__((ext_vector_type(4)));
typedef float    vf4    __attribute__((ext_vector_type(4)));

// ---- prep+pack: fp16 fragment-packed copies + exact f32 norms --------
// Packed layout: for 16-row block R, k-slice S (32 cols), a 1KB chunk of
// 64 lanes x 16B at chunk index (R*8 + S). Lane l = (kpart<<4)|rowl holds
// src[row = R*16 + rowl][k = S*32 + kpart*8 .. +8]  — exactly the
// mfma_f32_16x16x32_f16 A/B fragment so the GEMM loads it with ONE
// coalesced global_load_dwordx4 per fragment (no LDS, no barriers).
__global__ __launch_bounds__(256) void prep_pack(
    const float* __restrict__ x, const float* __restrict__ w,
    float* __restrict__ x2, float* __restrict__ w2,
    _Float16* __restrict__ xp, _Float16* __restrict__ wp) {
  int g    = blockIdx.x * 4 + (threadIdx.x >> 6);  // one wave per 16-row group
  int lane = threadIdx.x & 63;
  const float* src; _Float16* dst; float* nrm;
  if (g < M_ROWS / 16) {
    src = x + (size_t)g * 16 * K_DIM; dst = xp + (size_t)g * 8 * 512; nrm = x2 + g * 16;
  } else {
    int g2 = g - M_ROWS / 16;
    src = w + (size_t)g2 * 16 * K_DIM; dst = wp + (size_t)g2 * 8 * 512; nrm = w2 + g2 * 16;
  }
  int rowl = lane & 15, kpart = lane >> 4;
  float ss = 0.f;
  #pragma unroll
  for (int S = 0; S < 8; ++S) {
    const float* p = src + rowl * K_DIM + S * 32 + kpart * 8;
    float4 a = *(const float4*)p;
    float4 b = *(const float4*)(p + 4);
    ss += a.x*a.x + a.y*a.y + a.z*a.z + a.w*a.w
        + b.x*b.x + b.y*b.y + b.z*b.z + b.w*b.w;
    half8 h;
    h[0]=(_Float16)a.x; h[1]=(_Float16)a.y; h[2]=(_Float16)a.z; h[3]=(_Float16)a.w;
    h[4]=(_Float16)b.x; h[5]=(_Float16)b.y; h[6]=(_Float16)b.z; h[7]=(_Float16)b.w;
    *(half8*)(dst + S * 512 + lane * 8) = h;     // coalesced 1KB per wave
  }
  // lane covers 64 elems of row rowl; sum the 4 kpart-lanes per row
  ss += __shfl_xor(ss, 16);
  ss += __shfl_xor(ss, 32);
  if (lane < 16) nrm[lane] = ss;
}

// -------- 128x128 GEMM from packed fragments: no LDS staging, no K-loop
// barriers. Each wave: 64 coalesced 16B loads + 128 MFMAs, fully unrolled.
// MODE 0: per-row exp-sum partials.  MODE 1: write normalized softmax.
template <int MODE>
__global__ __launch_bounds__(256, 3) void gemm_pass(
    const _Float16* __restrict__ Ap, const _Float16* __restrict__ Bp,
    const float* __restrict__ x2g, const float* __restrict__ w2g,
    const float* __restrict__ invg,
    float* __restrict__ partials,
    float* __restrict__ out) {
  __shared__ float rowpart[2][128];   // MODE 0 cross-wave combine only

  // XCD partition (verified R2/R6): xcd owns 16 contiguous col-tiles;
  // col-tile varies fastest -> A-tile reused 16x consecutively from L2.
  int id   = blockIdx.x;            // grid = 64 row-tiles * 128 col-tiles = 8192
  int xcd  = id & 7;
  int rest = id >> 3;
  int ct   = xcd * 16 + (rest & 15);
  int rt   = rest >> 4;
  int brow = rt * 128;
  int bcol = ct * 128;

  int tid = threadIdx.x, lane = tid & 63, wid = tid >> 6;
  int wr = wid >> 1, wc = wid & 1;  // 2x2 waves, each 64x64 output

  int RA = rt * 8 + wr * 4;         // A 16-row-block base for this wave
  int RB = ct * 8 + wc * 4;         // B 16-row-block base

  vf4 acc[4][4] = {};

  #pragma unroll
  for (int S = 0; S < 8; ++S) {     // K=256 in 8 slices of 32
    half8 af[4], bf[4];
    #pragma unroll
    for (int m = 0; m < 4; ++m)
      af[m] = *(const half8*)(Ap + (((size_t)(RA + m) * 8 + S) << 9) + lane * 8);
    #pragma unroll
    for (int n = 0; n < 4; ++n)
      bf[n] = *(const half8*)(Bp + (((size_t)(RB + n) * 8 + S) << 9) + lane * 8);
    #pragma unroll
    for (int m = 0; m < 4; ++m)
      #pragma unroll
      for (int n = 0; n < 4; ++n)
        acc[m][n] = __builtin_amdgcn_mfma_f32_16x16x32_f16(af[m], bf[n], acc[m][n], 0, 0, 0);
  }

  if (MODE == 0) {
    // per-row sums of exp(-2*dist) over this tile's 128 cols
    #pragma unroll
    for (int m = 0; m < 4; ++m) {
      #pragma unroll
      for (int j = 0; j < 4; ++j) {
        int rl = wr * 64 + m * 16 + ((lane >> 4) << 2) + j;   // C/D: row=(lane>>4)*4+j
        float x2v = x2g[brow + rl];
        float sm = 0.f;
        #pragma unroll
        for (int n = 0; n < 4; ++n) {
          int cl = wc * 64 + n * 16 + (lane & 15);            // C/D: col=lane&15
          float d2 = fmaxf(x2v + w2g[bcol + cl] - 2.0f * acc[m][n][j], 0.0f);
          sm += __expf(-2.0f * sqrtf(d2));
        }
        sm += __shfl_xor(sm, 1);
        sm += __shfl_xor(sm, 2);
        sm += __shfl_xor(sm, 4);
        sm += __shfl_xor(sm, 8);
        if ((lane & 15) == 0) rowpart[wc][rl] = sm;
      }
    }
    __syncthreads();
    if (tid < 128)
      partials[(size_t)(brow + tid) * NTILE + ct] = rowpart[0][tid] + rowpart[1][tid];
  } else {
    // out = exp(-2*dist) * inv_rowsum
    #pragma unroll
    for (int m = 0; m < 4; ++m) {
      #pragma unroll
      for (int j = 0; j < 4; ++j) {
        int rl = wr * 64 + m * 16 + ((lane >> 4) << 2) + j;
        float x2v = x2g[brow + rl];
        float inv = invg[brow + rl];
        size_t rowbase = (size_t)(brow + rl) * N_COLS + bcol;
        #pragma unroll
        for (int n = 0; n < 4; ++n) {
          int cl = wc * 64 + n * 16 + (lane & 15);
          float d2 = fmaxf(x2v + w2g[bcol + cl] - 2.0f * acc[m][n][j], 0.0f);
          out[rowbase + cl] = __expf(-2.0f * sqrtf(d2)) * inv;
        }
      }
    }
  }
}

// ------------- reduce partials -> 1/rowsum, one wave per row -----------
__global__ __launch_bounds__(256) void reduce_inv(
    const float* __restrict__ partials, float* __restrict__ invg) {
  int row  = blockIdx.x * 4 + (threadIdx.x >> 6);
  int lane = threadIdx.x & 63;
  const float* p = partials + (size_t)row * NTILE;
  float s = p[lane] + p[lane + 64];   // NTILE == 128
  #pragma unroll
  for (int off = 32; off > 0; off >>= 1) s += __shfl_down(s, off);
  if (lane == 0) invg[row] = 1.0f / s;
}

// =============== fallback path (ws tiny): logits + row softmax ===============
__global__ __launch_bounds__(256, 2) void gemm_logit_f32(
    const float* __restrict__ xf, const float* __restrict__ wf,
    float* __restrict__ out, int mbase) {
  __shared__ _Float16 As[128 * 64];
  __shared__ _Float16 Bs[128 * 64];
  __shared__ float x2s[128];
  __shared__ float w2s[128];

  int id  = blockIdx.x;
  int xcd = id & 7;
  int rt  = (id >> 3) & 15;
  int c2  = id >> 7;
  int brow = mbase + rt * 128;
  int bcol = (xcd * 16 + c2) * 128;

  int tid = threadIdx.x, lane = tid & 63, wid = tid >> 6;
  int wr = wid >> 1, wc = wid & 1;

  vf4 acc[4][4] = {};

  {
    const float* src = (tid < 128) ? xf + (size_t)(brow + tid) * K_DIM
                                   : wf + (size_t)(bcol + tid - 128) * K_DIM;
    float s = 0.f;
    for (int i = 0; i < 64; ++i) {
      float4 v = ((const float4*)src)[i];
      s += v.x*v.x + v.y*v.y + v.z*v.z + v.w*v.w;
    }
    if (tid < 128) x2s[tid] = s; else w2s[tid - 128] = s;
  }

  for (int kk = 0; kk < K_DIM; kk += 64) {
    #pragma unroll
    for (int i = 0; i < 8; ++i) {
      int idx = i * 256 + tid;
      int r = idx >> 4, kq = idx & 15;
      float4 va = ((const float4*)(xf + (size_t)(brow + r) * K_DIM + kk))[kq];
      float4 vb = ((const float4*)(wf + (size_t)(bcol + r) * K_DIM + kk))[kq];
      half4v ha; ha[0]=(_Float16)va.x; ha[1]=(_Float16)va.y; ha[2]=(_Float16)va.z; ha[3]=(_Float16)va.w;
      half4v hb; hb[0]=(_Float16)vb.x; hb[1]=(_Float16)vb.y; hb[2]=(_Float16)vb.z; hb[3]=(_Float16)vb.w;
      *(half4v*)&As[r * 64 + kq * 4] = ha;
      *(half4v*)&Bs[r * 64 + kq * 4] = hb;
    }
    __syncthreads();
    #pragma unroll
    for (int ks = 0; ks < 2; ++ks) {
      half8 af[4], bf[4];
      #pragma unroll
      for (int m = 0; m < 4; ++m)
        af[m] = *(const half8*)&As[(wr*64 + m*16 + (lane & 15)) * 64 + ks*32 + (lane >> 4) * 8];
      #pragma unroll
      for (int n = 0; n < 4; ++n)
        bf[n] = *(const half8*)&Bs[(wc*64 + n*16 + (lane & 15)) * 64 + ks*32 + (lane >> 4) * 8];
      #pragma unroll
      for (int m = 0; m < 4; ++m)
        #pragma unroll
        for (int n = 0; n < 4; ++n)
          acc[m][n] = __builtin_amdgcn_mfma_f32_16x16x32_f16(af[m], bf[n], acc[m][n], 0, 0, 0);
    }
    __syncthreads();
  }

  #pragma unroll
  for (int m = 0; m < 4; ++m) {
    int rl = wr * 64 + m * 16 + ((lane >> 4) << 2);
    #pragma unroll
    for (int n = 0; n < 4; ++n) {
      int cl = wc * 64 + n * 16 + (lane & 15);
      int c  = bcol + cl;
      float w2v = w2s[cl];
      #pragma unroll
      for (int j = 0; j < 4; ++j) {
        int r = brow + rl + j;
        float d2 = fmaxf(x2s[rl + j] + w2v - 2.0f * acc[m][n][j], 0.0f);
        out[(size_t)r * N_COLS + c] = -2.0f * sqrtf(d2);
      }
    }
  }
}

__global__ __launch_bounds__(256) void softmax_norm(float* __restrict__ io, int mbase) {
  int row = mbase + blockIdx.x;
  float* p = io + (size_t)row * N_COLS;
  int tid = threadIdx.x;
  __shared__ float wsum[4];

  float4 v[16];
  float s = 0.f;
  #pragma unroll
  for (int i = 0; i < 16; ++i) {
    v[i] = ((const float4*)p)[i * 256 + tid];
    v[i].x = __expf(v[i].x); v[i].y = __expf(v[i].y);
    v[i].z = __expf(v[i].z); v[i].w = __expf(v[i].w);
    s += v[i].x + v[i].y + v[i].z + v[i].w;
  }
  #pragma unroll
  for (int off = 32; off > 0; off >>= 1) s += __shfl_down(s, off);
  if ((tid & 63) == 0) wsum[tid >> 6] = s;
  __syncthreads();
  float inv = 1.0f / (wsum[0] + wsum[1] + wsum[2] + wsum[3]);
  #pragma unroll
  for (int i = 0; i < 16; ++i) {
    float4 o = v[i];
    o.x *= inv; o.y *= inv; o.z *= inv; o.w *= inv;
    ((float4*)p)[i * 256 + tid] = o;
  }
}

extern "C" void kernel_launch(void* const* d_in, const int* in_sizes, int n_in,
                              void* d_out, int out_size, void* d_ws, size_t ws_size,
                              hipStream_t stream) {
  const float* x = (const float*)d_in[0];
  const float* w = (const float*)d_in[1];
  float* out = (float*)d_out;

  // ws layout: x2[8192] | w2[16384] | invsum[8192] | partials[8192*128] |
  //            xp fp16 packed [8192*256] | wp fp16 packed [16384*256]
  char* ws = (char*)d_ws;
  float* x2 = (float*)ws;
  float* w2 = x2 + M_ROWS;
  float* invsum = w2 + N_COLS;
  float* partials = invsum + M_ROWS;
  _Float16* xp = (_Float16*)(partials + (size_t)M_ROWS * NTILE);
  _Float16* wp = xp + (size_t)M_ROWS * K_DIM;
  const size_t need = ((size_t)(M_ROWS + N_COLS + M_ROWS) + (size_t)M_ROWS * NTILE) * 4
                    + (size_t)(M_ROWS + N_COLS) * K_DIM * 2;

  if (ws_size >= need) {
    prep_pack<<<(M_ROWS + N_COLS) / 16 / 4, 256, 0, stream>>>(x, w, x2, w2, xp, wp);
    gemm_pass<0><<<(M_ROWS / 128) * (N_COLS / 128), 256, 0, stream>>>(
        xp, wp, x2, w2, nullptr, partials, nullptr);
    reduce_inv<<<M_ROWS / 4, 256, 0, stream>>>(partials, invsum);
    gemm_pass<1><<<(M_ROWS / 128) * (N_COLS / 128), 256, 0, stream>>>(
        xp, wp, x2, w2, invsum, nullptr, out);
  } else {
    for (int c = 0; c < NCHUNK; ++c) {
      int mbase = c * CHUNK;
      gemm_logit_f32<<<(CHUNK / 128) * (N_COLS / 128), 256, 0, stream>>>(
          x, w, out, mbase);
      softmax_norm<<<CHUNK, 256, 0, stream>>>(out, mbase);
    }
  }
}

// Round 8
// 336.019 us; speedup vs baseline: 1.1437x; 1.1437x over previous
//
#include <hip/hip_runtime.h>
#include <math.h>
#include <stdint.h>

#define M_ROWS 8192
#define N_COLS 16384
#define K_DIM  256
#define NTILE  (N_COLS / 128)   // 128 col tiles
#define CROWS  2048             // rows per chunk (xw chunk = 64MB fp16, LLC-resident)
#define NCHUNK (M_ROWS / CROWS)

typedef _Float16 half8  __attribute__((ext_vector_type(8)));
typedef _Float16 half4v __attribute__((ext_vector_type(4)));
typedef float    vf4    __attribute__((ext_vector_type(4)));

__device__ __forceinline__ void gload16(const void* g, void* lds) {
  // async global->LDS, 16B per lane; LDS dest = wave-uniform base + lane*16
  __builtin_amdgcn_global_load_lds(
      (__attribute__((address_space(1))) void*)(void*)g,
      (__attribute__((address_space(3))) void*)lds, 16, 0, 0);
}

// ---------------- prep: fp16 copies + exact f32 norms -----------------
__global__ __launch_bounds__(256) void prep_kernel(
    const float* __restrict__ x, const float* __restrict__ w,
    float* __restrict__ x2, float* __restrict__ w2,
    _Float16* __restrict__ xh, _Float16* __restrict__ wh) {
  int row  = blockIdx.x * 4 + (threadIdx.x >> 6);  // one wave per row
  int lane = threadIdx.x & 63;
  const float* src; _Float16* dst; float* nrm;
  if (row < M_ROWS) {
    src = x + (size_t)row * K_DIM; dst = xh + (size_t)row * K_DIM; nrm = x2 + row;
  } else {
    int r = row - M_ROWS;
    src = w + (size_t)r * K_DIM; dst = wh + (size_t)r * K_DIM; nrm = w2 + r;
  }
  float4 v = ((const float4*)src)[lane];           // 64 lanes x 4 = 256
  float s = v.x*v.x + v.y*v.y + v.z*v.z + v.w*v.w;
  #pragma unroll
  for (int off = 32; off > 0; off >>= 1) s += __shfl_down(s, off);
  if (lane == 0) *nrm = s;
  half4v h; h[0]=(_Float16)v.x; h[1]=(_Float16)v.y; h[2]=(_Float16)v.z; h[3]=(_Float16)v.w;
  ((half4v*)dst)[lane] = h;
}

// -------- 128x128xBK64 GEMM (R6-verified: T2 swizzle per rule #21,
// occupancy 3). One 2048-row chunk: computes exp-row-partials AND stores
// xw fp16 into the chunk-shared LLC-resident buffer.
__global__ __launch_bounds__(256, 3) void gemm_xw(
    const _Float16* __restrict__ A, const _Float16* __restrict__ Bm,
    const float* __restrict__ x2g, const float* __restrict__ w2g,
    float* __restrict__ partials, _Float16* __restrict__ xwc, int mbase) {
  __shared__ _Float16 As[128 * 64];   // 16KB, swizzled contents
  __shared__ _Float16 Bs[128 * 64];   // 16KB
  __shared__ float x2s[128];
  __shared__ float w2s[128];
  __shared__ float rowpart[2][128];

  // XCD partition: xcd owns 16 contiguous col-tiles (w slice 1MB, L2-resident)
  int id   = blockIdx.x;            // grid = 16 row-tiles * 128 col-tiles = 2048
  int xcd  = id & 7;
  int rest = id >> 3;               // 0..255
  int ct   = xcd * 16 + (rest & 15);
  int rt   = rest >> 4;             // 0..15
  int browl = rt * 128;             // chunk-local
  int brow  = mbase + browl;        // global
  int bcol  = ct * 128;

  int tid = threadIdx.x, lane = tid & 63, wid = tid >> 6;
  int wr = wid >> 1, wc = wid & 1;  // 2x2 waves, each 64x64 output

  if (tid < 128) x2s[tid] = x2g[brow + tid];
  else           w2s[tid - 128] = w2g[bcol + tid - 128];

  vf4 acc[4][4] = {};

  for (int kk = 0; kk < K_DIM; kk += 64) {
    // linear gload_lds dest + inverse-swizzled global SOURCE (involution)
    #pragma unroll
    for (int i = 0; i < 4; ++i) {
      int seg = wid * 4 + i;
      int r   = seg * 8 + (lane >> 3);
      int colhalf = ((lane & 7) * 8) ^ ((lane >> 3) << 3);   // fp16 elems
      gload16(A  + (size_t)(brow + r) * K_DIM + kk + colhalf, (char*)As + seg * 1024);
      gload16(Bm + (size_t)(bcol + r) * K_DIM + kk + colhalf, (char*)Bs + seg * 1024);
    }
    __syncthreads();

    #pragma unroll
    for (int ks = 0; ks < 2; ++ks) {          // two K=32 MFMA steps per BK=64
      half8 af[4], bf[4];
      int cb = ks * 64 + (lane >> 4) * 16;    // column byte within 128B row
      #pragma unroll
      for (int m = 0; m < 4; ++m) {
        int ra = wr * 64 + m * 16 + (lane & 15);
        af[m] = *(const half8*)((const char*)As + ra * 128 + (cb ^ ((ra & 7) << 4)));
      }
      #pragma unroll
      for (int n = 0; n < 4; ++n) {
        int rb = wc * 64 + n * 16 + (lane & 15);
        bf[n] = *(const half8*)((const char*)Bs + rb * 128 + (cb ^ ((rb & 7) << 4)));
      }
      #pragma unroll
      for (int m = 0; m < 4; ++m)
        #pragma unroll
        for (int n = 0; n < 4; ++n)
          acc[m][n] = __builtin_amdgcn_mfma_f32_16x16x32_f16(af[m], bf[n], acc[m][n], 0, 0, 0);
    }
    __syncthreads();
  }

  // epilogue: per-row exp-sums over 128 cols + fp16 xw store (chunk-local)
  #pragma unroll
  for (int m = 0; m < 4; ++m) {
    #pragma unroll
    for (int j = 0; j < 4; ++j) {
      int rl = wr * 64 + m * 16 + ((lane >> 4) << 2) + j;   // C/D: row=(lane>>4)*4+j
      float x2v = x2s[rl];
      size_t rowbase = (size_t)(browl + rl) * N_COLS + bcol;
      float sm = 0.f;
      #pragma unroll
      for (int n = 0; n < 4; ++n) {
        int cl = wc * 64 + n * 16 + (lane & 15);            // C/D: col=lane&15
        float xwv = acc[m][n][j];
        float d2 = fmaxf(x2v + w2s[cl] - 2.0f * xwv, 0.0f);
        sm += __expf(-2.0f * sqrtf(d2));
        xwc[rowbase + cl] = (_Float16)xwv;                  // L2/LLC write
      }
      sm += __shfl_xor(sm, 1);
      sm += __shfl_xor(sm, 2);
      sm += __shfl_xor(sm, 4);
      sm += __shfl_xor(sm, 8);
      if ((lane & 15) == 0) rowpart[wc][rl] = sm;
    }
  }
  __syncthreads();
  if (tid < 128)
    partials[(size_t)(brow + tid) * NTILE + ct] = rowpart[0][tid] + rowpart[1][tid];
}

// ------------- reduce partials -> 1/rowsum, one wave per row -----------
__global__ __launch_bounds__(256) void reduce_inv(
    const float* __restrict__ partials, float* __restrict__ invg, int mbase) {
  int row  = mbase + blockIdx.x * 4 + (threadIdx.x >> 6);
  int lane = threadIdx.x & 63;
  const float* p = partials + (size_t)row * NTILE;
  float s = p[lane] + p[lane + 64];   // NTILE == 128
  #pragma unroll
  for (int off = 32; off > 0; off >>= 1) s += __shfl_down(s, off);
  if (lane == 0) invg[row] = 1.0f / s;
}

// ------ finalize chunk: out = exp(-2*sqrt(x2+w2-2*xw)) * inv  ----------
// reads xw fp16 (LLC-resident), writes 128MB f32 out slice (coalesced)
__global__ __launch_bounds__(256) void finalize_kernel(
    const _Float16* __restrict__ xwc, const float* __restrict__ x2g,
    const float* __restrict__ w2g, const float* __restrict__ invg,
    float* __restrict__ out, int mbase) {
  const size_t NV = (size_t)CROWS * N_COLS / 8;
  size_t stride = (size_t)gridDim.x * blockDim.x;
  float* outc = out + (size_t)mbase * N_COLS;
  for (size_t i = (size_t)blockIdx.x * blockDim.x + threadIdx.x; i < NV; i += stride) {
    size_t base = i * 8;
    int rowl = (int)(base >> 14);            // / N_COLS
    int col  = (int)(base & (N_COLS - 1));
    half8 h = *(const half8*)(xwc + base);
    float x2v = x2g[mbase + rowl];
    float inv = invg[mbase + rowl];
    float4 wa = *(const float4*)(w2g + col);
    float4 wb = *(const float4*)(w2g + col + 4);
    float4 o0, o1;
    o0.x = __expf(-2.f * sqrtf(fmaxf(x2v + wa.x - 2.f * (float)h[0], 0.f))) * inv;
    o0.y = __expf(-2.f * sqrtf(fmaxf(x2v + wa.y - 2.f * (float)h[1], 0.f))) * inv;
    o0.z = __expf(-2.f * sqrtf(fmaxf(x2v + wa.z - 2.f * (float)h[2], 0.f))) * inv;
    o0.w = __expf(-2.f * sqrtf(fmaxf(x2v + wa.w - 2.f * (float)h[3], 0.f))) * inv;
    o1.x = __expf(-2.f * sqrtf(fmaxf(x2v + wb.x - 2.f * (float)h[4], 0.f))) * inv;
    o1.y = __expf(-2.f * sqrtf(fmaxf(x2v + wb.y - 2.f * (float)h[5], 0.f))) * inv;
    o1.z = __expf(-2.f * sqrtf(fmaxf(x2v + wb.z - 2.f * (float)h[6], 0.f))) * inv;
    o1.w = __expf(-2.f * sqrtf(fmaxf(x2v + wb.w - 2.f * (float)h[7], 0.f))) * inv;
    *(float4*)(outc + base)     = o0;
    *(float4*)(outc + base + 4) = o1;
  }
}

// ====== tier B (R6-verified two-pass recompute) + tiny-ws fallback ======
template <int MODE>
__global__ __launch_bounds__(256, 3) void gemm_pass(
    const _Float16* __restrict__ A, const _Float16* __restrict__ Bm,
    const float* __restrict__ x2g, const float* __restrict__ w2g,
    const float* __restrict__ invg,
    float* __restrict__ partials,
    float* __restrict__ out) {
  __shared__ _Float16 As[128 * 64];
  __shared__ _Float16 Bs[128 * 64];
  __shared__ float x2s[128];
  __shared__ float w2s[128];
  __shared__ float invs[128];
  __shared__ float rowpart[2][128];

  int id   = blockIdx.x;            // grid = 64 row-tiles * 128 col-tiles = 8192
  int xcd  = id & 7;
  int rest = id >> 3;
  int ct   = xcd * 16 + (rest & 15);
  int rt   = rest >> 4;
  int brow = rt * 128;
  int bcol = ct * 128;

  int tid = threadIdx.x, lane = tid & 63, wid = tid >> 6;
  int wr = wid >> 1, wc = wid & 1;

  if (tid < 128) {
    x2s[tid] = x2g[brow + tid];
    if (MODE == 1) invs[tid] = invg[brow + tid];
  } else {
    w2s[tid - 128] = w2g[bcol + tid - 128];
  }

  vf4 acc[4][4] = {};

  for (int kk = 0; kk < K_DIM; kk += 64) {
    #pragma unroll
    for (int i = 0; i < 4; ++i) {
      int seg = wid * 4 + i;
      int r   = seg * 8 + (lane >> 3);
      int colhalf = ((lane & 7) * 8) ^ ((lane >> 3) << 3);
      gload16(A  + (size_t)(brow + r) * K_DIM + kk + colhalf, (char*)As + seg * 1024);
      gload16(Bm + (size_t)(bcol + r) * K_DIM + kk + colhalf, (char*)Bs + seg * 1024);
    }
    __syncthreads();
    #pragma unroll
    for (int ks = 0; ks < 2; ++ks) {
      half8 af[4], bf[4];
      int cb = ks * 64 + (lane >> 4) * 16;
      #pragma unroll
      for (int m = 0; m < 4; ++m) {
        int ra = wr * 64 + m * 16 + (lane & 15);
        af[m] = *(const half8*)((const char*)As + ra * 128 + (cb ^ ((ra & 7) << 4)));
      }
      #pragma unroll
      for (int n = 0; n < 4; ++n) {
        int rb = wc * 64 + n * 16 + (lane & 15);
        bf[n] = *(const half8*)((const char*)Bs + rb * 128 + (cb ^ ((rb & 7) << 4)));
      }
      #pragma unroll
      for (int m = 0; m < 4; ++m)
        #pragma unroll
        for (int n = 0; n < 4; ++n)
          acc[m][n] = __builtin_amdgcn_mfma_f32_16x16x32_f16(af[m], bf[n], acc[m][n], 0, 0, 0);
    }
    __syncthreads();
  }

  if (MODE == 0) {
    #pragma unroll
    for (int m = 0; m < 4; ++m) {
      #pragma unroll
      for (int j = 0; j < 4; ++j) {
        int rl = wr * 64 + m * 16 + ((lane >> 4) << 2) + j;
        float x2v = x2s[rl];
        float sm = 0.f;
        #pragma unroll
        for (int n = 0; n < 4; ++n) {
          int cl = wc * 64 + n * 16 + (lane & 15);
          float d2 = fmaxf(x2v + w2s[cl] - 2.0f * acc[m][n][j], 0.0f);
          sm += __expf(-2.0f * sqrtf(d2));
        }
        sm += __shfl_xor(sm, 1);
        sm += __shfl_xor(sm, 2);
        sm += __shfl_xor(sm, 4);
        sm += __shfl_xor(sm, 8);
        if ((lane & 15) == 0) rowpart[wc][rl] = sm;
      }
    }
    __syncthreads();
    if (tid < 128)
      partials[(size_t)(brow + tid) * NTILE + ct] = rowpart[0][tid] + rowpart[1][tid];
  } else {
    #pragma unroll
    for (int m = 0; m < 4; ++m) {
      #pragma unroll
      for (int j = 0; j < 4; ++j) {
        int rl = wr * 64 + m * 16 + ((lane >> 4) << 2) + j;
        float x2v = x2s[rl];
        float inv = invs[rl];
        size_t rowbase = (size_t)(brow + rl) * N_COLS + bcol;
        #pragma unroll
        for (int n = 0; n < 4; ++n) {
          int cl = wc * 64 + n * 16 + (lane & 15);
          float d2 = fmaxf(x2v + w2s[cl] - 2.0f * acc[m][n][j], 0.0f);
          out[rowbase + cl] = __expf(-2.0f * sqrtf(d2)) * inv;
        }
      }
    }
  }
}

__global__ __launch_bounds__(256) void reduce_inv_full(
    const float* __restrict__ partials, float* __restrict__ invg) {
  int row  = blockIdx.x * 4 + (threadIdx.x >> 6);
  int lane = threadIdx.x & 63;
  const float* p = partials + (size_t)row * NTILE;
  float s = p[lane] + p[lane + 64];
  #pragma unroll
  for (int off = 32; off > 0; off >>= 1) s += __shfl_down(s, off);
  if (lane == 0) invg[row] = 1.0f / s;
}

extern "C" void kernel_launch(void* const* d_in, const int* in_sizes, int n_in,
                              void* d_out, int out_size, void* d_ws, size_t ws_size,
                              hipStream_t stream) {
  const float* x = (const float*)d_in[0];
  const float* w = (const float*)d_in[1];
  float* out = (float*)d_out;

  // ws layout: x2[8192] | w2[16384] | invsum[8192] | partials[8192*128] |
  //            xh fp16 [8192*256] | wh fp16 [16384*256] | xwc fp16 [2048*16384]
  char* ws = (char*)d_ws;
  float* x2 = (float*)ws;
  float* w2 = x2 + M_ROWS;
  float* invsum = w2 + N_COLS;
  float* partials = invsum + M_ROWS;
  _Float16* xh = (_Float16*)(partials + (size_t)M_ROWS * NTILE);
  _Float16* wh = xh + (size_t)M_ROWS * K_DIM;
  _Float16* xwc = wh + (size_t)N_COLS * K_DIM;
  const size_t needB = ((size_t)(M_ROWS + N_COLS + M_ROWS) + (size_t)M_ROWS * NTILE) * 4
                     + (size_t)(M_ROWS + N_COLS) * K_DIM * 2;
  const size_t needA = needB + (size_t)CROWS * N_COLS * 2;

  if (ws_size >= needA) {
    // tier A: chunked single-GEMM + LLC-resident xw + memory-bound finalize
    prep_kernel<<<(M_ROWS + N_COLS) / 4, 256, 0, stream>>>(x, w, x2, w2, xh, wh);
    for (int c = 0; c < NCHUNK; ++c) {
      int mbase = c * CROWS;
      gemm_xw<<<(CROWS / 128) * (N_COLS / 128), 256, 0, stream>>>(
          xh, wh, x2, w2, partials, xwc, mbase);
      reduce_inv<<<CROWS / 4, 256, 0, stream>>>(partials, invsum, mbase);
      finalize_kernel<<<2048, 256, 0, stream>>>(xwc, x2, w2, invsum, out, mbase);
    }
  } else if (ws_size >= needB) {
    // tier B: R6 two-pass recompute
    prep_kernel<<<(M_ROWS + N_COLS) / 4, 256, 0, stream>>>(x, w, x2, w2, xh, wh);
    gemm_pass<0><<<(M_ROWS / 128) * (N_COLS / 128), 256, 0, stream>>>(
        xh, wh, x2, w2, nullptr, partials, nullptr);
    reduce_inv_full<<<M_ROWS / 4, 256, 0, stream>>>(partials, invsum);
    gemm_pass<1><<<(M_ROWS / 128) * (N_COLS / 128), 256, 0, stream>>>(
        xh, wh, x2, w2, invsum, nullptr, out);
  }
  // (problem guarantees a large ws; tiers cover all realistic sizes)
}

// Round 9
// 334.468 us; speedup vs baseline: 1.1490x; 1.0046x over previous
//
#include <hip/hip_runtime.h>
#include <math.h>
#include <stdint.h>

#define M_ROWS 8192
#define N_COLS 16384
#define K_DIM  256
#define NTILE  (N_COLS / 128)   // 128 col tiles
#define CHUNK  2048             // fallback path only
#define NCHUNK 4

typedef _Float16 half8  __attribute__((ext_vector_type(8)));
typedef _Float16 half4v __attribute__((ext_vector_type(4)));
typedef float    vf4    __attribute__((ext_vector_type(4)));

__device__ __forceinline__ void gload16(const void* g, void* lds) {
  // async global->LDS, 16B per lane; LDS dest = wave-uniform base + lane*16
  __builtin_amdgcn_global_load_lds(
      (__attribute__((address_space(1))) void*)(void*)g,
      (__attribute__((address_space(3))) void*)lds, 16, 0, 0);
}

// ---------------- prep: fp16 copies + exact f32 norms -----------------
__global__ __launch_bounds__(256) void prep_kernel(
    const float* __restrict__ x, const float* __restrict__ w,
    float* __restrict__ x2, float* __restrict__ w2,
    _Float16* __restrict__ xh, _Float16* __restrict__ wh) {
  int row  = blockIdx.x * 4 + (threadIdx.x >> 6);  // one wave per row
  int lane = threadIdx.x & 63;
  const float* src; _Float16* dst; float* nrm;
  if (row < M_ROWS) {
    src = x + (size_t)row * K_DIM; dst = xh + (size_t)row * K_DIM; nrm = x2 + row;
  } else {
    int r = row - M_ROWS;
    src = w + (size_t)r * K_DIM; dst = wh + (size_t)r * K_DIM; nrm = w2 + r;
  }
  float4 v = ((const float4*)src)[lane];           // 64 lanes x 4 = 256
  float s = v.x*v.x + v.y*v.y + v.z*v.z + v.w*v.w;
  #pragma unroll
  for (int off = 32; off > 0; off >>= 1) s += __shfl_down(s, off);
  if (lane == 0) *nrm = s;
  half4v h; h[0]=(_Float16)v.x; h[1]=(_Float16)v.y; h[2]=(_Float16)v.z; h[3]=(_Float16)v.w;
  ((half4v*)dst)[lane] = h;
}

// -------- 128x128xBK64 GEMM (R6 structure: T2 swizzle per rule #21).
// ONLY change vs R6: __launch_bounds__(256, 4) -> VGPR cap 128 ->
// 4 blocks/CU = 16 waves/CU (was 12). Occupancy ladder: 8w=392us,
// 12w=312us; predicting ~275us at 16w if no K-loop spill.
// MODE 0: per-row exp-sum partials.  MODE 1: write normalized softmax.
template <int MODE>
__global__ __launch_bounds__(256, 4) void gemm_pass(
    const _Float16* __restrict__ A, const _Float16* __restrict__ Bm,
    const float* __restrict__ x2g, const float* __restrict__ w2g,
    const float* __restrict__ invg,
    float* __restrict__ partials,
    float* __restrict__ out) {
  __shared__ _Float16 As[128 * 64];   // 16KB, swizzled contents
  __shared__ _Float16 Bs[128 * 64];   // 16KB
  __shared__ float x2s[128];
  __shared__ float w2s[128];
  __shared__ float invs[128];
  __shared__ float rowpart[2][128];

  // XCD partition: xcd = id&7 owns 16 contiguous col-tiles (w slice 1MB, L2-resident);
  // within an XCD, col-tile varies fastest -> A-tile reused 16x consecutively.
  int id   = blockIdx.x;            // grid = 64 row-tiles * 128 col-tiles = 8192
  int xcd  = id & 7;
  int rest = id >> 3;               // 0..1023
  int ct   = xcd * 16 + (rest & 15);
  int rt   = rest >> 4;             // 0..63
  int brow = rt * 128;
  int bcol = ct * 128;

  int tid = threadIdx.x, lane = tid & 63, wid = tid >> 6;
  int wr = wid >> 1, wc = wid & 1;  // 2x2 waves, each 64x64 output

  if (tid < 128) {
    x2s[tid] = x2g[brow + tid];
    if (MODE == 1) invs[tid] = invg[brow + tid];
  } else {
    w2s[tid - 128] = w2g[bcol + tid - 128];
  }

  vf4 acc[4][4] = {};

  for (int kk = 0; kk < K_DIM; kk += 64) {
    // stage: seg = 8 rows of [row][64] fp16 (1KB). LDS dest linear
    // (base + lane*16); global source column pre-swizzled so that
    // LDS[row][cb] = global[row][cb ^ ((row&7)<<4)]  (involution).
    #pragma unroll
    for (int i = 0; i < 4; ++i) {
      int seg = wid * 4 + i;
      int r   = seg * 8 + (lane >> 3);
      int colhalf = ((lane & 7) * 8) ^ ((lane >> 3) << 3);   // fp16 elems
      gload16(A  + (size_t)(brow + r) * K_DIM + kk + colhalf, (char*)As + seg * 1024);
      gload16(Bm + (size_t)(bcol + r) * K_DIM + kk + colhalf, (char*)Bs + seg * 1024);
    }
    __syncthreads();   // compiler drains vmcnt(0) before s_barrier

    #pragma unroll
    for (int ks = 0; ks < 2; ++ks) {          // two K=32 MFMA steps per BK=64
      half8 af[4], bf[4];
      int cb = ks * 64 + (lane >> 4) * 16;    // column byte within 128B row
      #pragma unroll
      for (int m = 0; m < 4; ++m) {
        int ra = wr * 64 + m * 16 + (lane & 15);
        af[m] = *(const half8*)((const char*)As + ra * 128 + (cb ^ ((ra & 7) << 4)));
      }
      #pragma unroll
      for (int n = 0; n < 4; ++n) {
        int rb = wc * 64 + n * 16 + (lane & 15);
        bf[n] = *(const half8*)((const char*)Bs + rb * 128 + (cb ^ ((rb & 7) << 4)));
      }
      #pragma unroll
      for (int m = 0; m < 4; ++m)
        #pragma unroll
        for (int n = 0; n < 4; ++n)
          acc[m][n] = __builtin_amdgcn_mfma_f32_16x16x32_f16(af[m], bf[n], acc[m][n], 0, 0, 0);
    }
    __syncthreads();
  }

  if (MODE == 0) {
    // epilogue: per-row sums of exp(-2*dist) over this tile's 128 cols
    #pragma unroll
    for (int m = 0; m < 4; ++m) {
      #pragma unroll
      for (int j = 0; j < 4; ++j) {
        int rl = wr * 64 + m * 16 + ((lane >> 4) << 2) + j;   // C/D: row=(lane>>4)*4+j
        float x2v = x2s[rl];
        float sm = 0.f;
        #pragma unroll
        for (int n = 0; n < 4; ++n) {
          int cl = wc * 64 + n * 16 + (lane & 15);            // C/D: col=lane&15
          float d2 = fmaxf(x2v + w2s[cl] - 2.0f * acc[m][n][j], 0.0f);
          sm += __expf(-2.0f * sqrtf(d2));
        }
        // reduce across the 16 lanes (lane&15) sharing this row
        sm += __shfl_xor(sm, 1);
        sm += __shfl_xor(sm, 2);
        sm += __shfl_xor(sm, 4);
        sm += __shfl_xor(sm, 8);
        if ((lane & 15) == 0) rowpart[wc][rl] = sm;
      }
    }
    __syncthreads();
    if (tid < 128)
      partials[(size_t)(brow + tid) * NTILE + ct] = rowpart[0][tid] + rowpart[1][tid];
  } else {
    // epilogue: out = exp(-2*dist) * inv_rowsum
    #pragma unroll
    for (int m = 0; m < 4; ++m) {
      #pragma unroll
      for (int j = 0; j < 4; ++j) {
        int rl = wr * 64 + m * 16 + ((lane >> 4) << 2) + j;
        float x2v = x2s[rl];
        float inv = invs[rl];
        size_t rowbase = (size_t)(brow + rl) * N_COLS + bcol;
        #pragma unroll
        for (int n = 0; n < 4; ++n) {
          int cl = wc * 64 + n * 16 + (lane & 15);
          float d2 = fmaxf(x2v + w2s[cl] - 2.0f * acc[m][n][j], 0.0f);
          out[rowbase + cl] = __expf(-2.0f * sqrtf(d2)) * inv;
        }
      }
    }
  }
}

// ------------- reduce partials -> 1/rowsum, one wave per row -----------
__global__ __launch_bounds__(256) void reduce_inv(
    const float* __restrict__ partials, float* __restrict__ invg) {
  int row  = blockIdx.x * 4 + (threadIdx.x >> 6);
  int lane = threadIdx.x & 63;
  const float* p = partials + (size_t)row * NTILE;
  float s = p[lane] + p[lane + 64];   // NTILE == 128
  #pragma unroll
  for (int off = 32; off > 0; off >>= 1) s += __shfl_down(s, off);
  if (lane == 0) invg[row] = 1.0f / s;
}

// =============== fallback path (ws tiny): logits + row softmax ===============
__global__ __launch_bounds__(256, 2) void gemm_logit_f32(
    const float* __restrict__ xf, const float* __restrict__ wf,
    float* __restrict__ out, int mbase) {
  __shared__ _Float16 As[128 * 64];
  __shared__ _Float16 Bs[128 * 64];
  __shared__ float x2s[128];
  __shared__ float w2s[128];

  int id  = blockIdx.x;
  int xcd = id & 7;
  int rt  = (id >> 3) & 15;
  int c2  = id >> 7;
  int brow = mbase + rt * 128;
  int bcol = (xcd * 16 + c2) * 128;

  int tid = threadIdx.x, lane = tid & 63, wid = tid >> 6;
  int wr = wid >> 1, wc = wid & 1;

  vf4 acc[4][4] = {};

  {
    const float* src = (tid < 128) ? xf + (size_t)(brow + tid) * K_DIM
                                   : wf + (size_t)(bcol + tid - 128) * K_DIM;
    float s = 0.f;
    for (int i = 0; i < 64; ++i) {
      float4 v = ((const float4*)src)[i];
      s += v.x*v.x + v.y*v.y + v.z*v.z + v.w*v.w;
    }
    if (tid < 128) x2s[tid] = s; else w2s[tid - 128] = s;
  }

  for (int kk = 0; kk < K_DIM; kk += 64) {
    #pragma unroll
    for (int i = 0; i < 8; ++i) {
      int idx = i * 256 + tid;
      int r = idx >> 4, kq = idx & 15;
      float4 va = ((const float4*)(xf + (size_t)(brow + r) * K_DIM + kk))[kq];
      float4 vb = ((const float4*)(wf + (size_t)(bcol + r) * K_DIM + kk))[kq];
      half4v ha; ha[0]=(_Float16)va.x; ha[1]=(_Float16)va.y; ha[2]=(_Float16)va.z; ha[3]=(_Float16)va.w;
      half4v hb; hb[0]=(_Float16)vb.x; hb[1]=(_Float16)vb.y; hb[2]=(_Float16)vb.z; hb[3]=(_Float16)vb.w;
      *(half4v*)&As[r * 64 + kq * 4] = ha;
      *(half4v*)&Bs[r * 64 + kq * 4] = hb;
    }
    __syncthreads();
    #pragma unroll
    for (int ks = 0; ks < 2; ++ks) {
      half8 af[4], bf[4];
      #pragma unroll
      for (int m = 0; m < 4; ++m)
        af[m] = *(const half8*)&As[(wr*64 + m*16 + (lane & 15)) * 64 + ks*32 + (lane >> 4) * 8];
      #pragma unroll
      for (int n = 0; n < 4; ++n)
        bf[n] = *(const half8*)&Bs[(wc*64 + n*16 + (lane & 15)) * 64 + ks*32 + (lane >> 4) * 8];
      #pragma unroll
      for (int m = 0; m < 4; ++m)
        #pragma unroll
        for (int n = 0; n < 4; ++n)
          acc[m][n] = __builtin_amdgcn_mfma_f32_16x16x32_f16(af[m], bf[n], acc[m][n], 0, 0, 0);
    }
    __syncthreads();
  }

  #pragma unroll
  for (int m = 0; m < 4; ++m) {
    int rl = wr * 64 + m * 16 + ((lane >> 4) << 2);
    #pragma unroll
    for (int n = 0; n < 4; ++n) {
      int cl = wc * 64 + n * 16 + (lane & 15);
      int c  = bcol + cl;
      float w2v = w2s[cl];
      #pragma unroll
      for (int j = 0; j < 4; ++j) {
        int r = brow + rl + j;
        float d2 = fmaxf(x2s[rl + j] + w2v - 2.0f * acc[m][n][j], 0.0f);
        out[(size_t)r * N_COLS + c] = -2.0f * sqrtf(d2);
      }
    }
  }
}

__global__ __launch_bounds__(256) void softmax_norm(float* __restrict__ io, int mbase) {
  int row = mbase + blockIdx.x;
  float* p = io + (size_t)row * N_COLS;
  int tid = threadIdx.x;
  __shared__ float wsum[4];

  float4 v[16];
  float s = 0.f;
  #pragma unroll
  for (int i = 0; i < 16; ++i) {
    v[i] = ((const float4*)p)[i * 256 + tid];
    v[i].x = __expf(v[i].x); v[i].y = __expf(v[i].y);
    v[i].z = __expf(v[i].z); v[i].w = __expf(v[i].w);
    s += v[i].x + v[i].y + v[i].z + v[i].w;
  }
  #pragma unroll
  for (int off = 32; off > 0; off >>= 1) s += __shfl_down(s, off);
  if ((tid & 63) == 0) wsum[tid >> 6] = s;
  __syncthreads();
  float inv = 1.0f / (wsum[0] + wsum[1] + wsum[2] + wsum[3]);
  #pragma unroll
  for (int i = 0; i < 16; ++i) {
    float4 o = v[i];
    o.x *= inv; o.y *= inv; o.z *= inv; o.w *= inv;
    ((float4*)p)[i * 256 + tid] = o;
  }
}

extern "C" void kernel_launch(void* const* d_in, const int* in_sizes, int n_in,
                              void* d_out, int out_size, void* d_ws, size_t ws_size,
                              hipStream_t stream) {
  const float* x = (const float*)d_in[0];
  const float* w = (const float*)d_in[1];
  float* out = (float*)d_out;

  // ws layout: x2[8192] | w2[16384] | invsum[8192] | partials[8192*128] |
  //            xh fp16 [8192*256] | wh fp16 [16384*256]
  char* ws = (char*)d_ws;
  float* x2 = (float*)ws;
  float* w2 = x2 + M_ROWS;
  float* invsum = w2 + N_COLS;
  float* partials = invsum + M_ROWS;
  _Float16* xh = (_Float16*)(partials + (size_t)M_ROWS * NTILE);
  _Float16* wh = xh + (size_t)M_ROWS * K_DIM;
  const size_t need = ((size_t)(M_ROWS + N_COLS + M_ROWS) + (size_t)M_ROWS * NTILE) * 4
                    + (size_t)(M_ROWS + N_COLS) * K_DIM * 2;

  if (ws_size >= need) {
    prep_kernel<<<(M_ROWS + N_COLS) / 4, 256, 0, stream>>>(x, w, x2, w2, xh, wh);
    gemm_pass<0><<<(M_ROWS / 128) * (N_COLS / 128), 256, 0, stream>>>(
        xh, wh, x2, w2, nullptr, partials, nullptr);
    reduce_inv<<<M_ROWS / 4, 256, 0, stream>>>(partials, invsum);
    gemm_pass<1><<<(M_ROWS / 128) * (N_COLS / 128), 256, 0, stream>>>(
        xh, wh, x2, w2, invsum, nullptr, out);
  } else {
    for (int c = 0; c < NCHUNK; ++c) {
      int mbase = c * CHUNK;
      gemm_logit_f32<<<(CHUNK / 128) * (N_COLS / 128), 256, 0, stream>>>(
          x, w, out, mbase);
      softmax_norm<<<CHUNK, 256, 0, stream>>>(out, mbase);
    }
  }
}

// Round 10
// 313.177 us; speedup vs baseline: 1.2271x; 1.0680x over previous
//
#include <hip/hip_runtime.h>
#include <math.h>
#include <stdint.h>

#define M_ROWS 8192
#define N_COLS 16384
#define K_DIM  256
#define NTILE  (N_COLS / 128)   // 128 col tiles
#define CHUNK  2048             // fallback path only
#define NCHUNK 4

typedef _Float16 half8  __attribute__((ext_vector_type(8)));
typedef _Float16 half4v __attribute__((ext_vector_type(4)));
typedef float    vf4    __attribute__((ext_vector_type(4)));

__device__ __forceinline__ void gload16(const void* g, void* lds) {
  // async global->LDS, 16B per lane; LDS dest = wave-uniform base + lane*16
  __builtin_amdgcn_global_load_lds(
      (__attribute__((address_space(1))) void*)(void*)g,
      (__attribute__((address_space(3))) void*)lds, 16, 0, 0);
}

// ---------------- prep: fp16 copies + exact f32 norms -----------------
__global__ __launch_bounds__(256) void prep_kernel(
    const float* __restrict__ x, const float* __restrict__ w,
    float* __restrict__ x2, float* __restrict__ w2,
    _Float16* __restrict__ xh, _Float16* __restrict__ wh) {
  int row  = blockIdx.x * 4 + (threadIdx.x >> 6);  // one wave per row
  int lane = threadIdx.x & 63;
  const float* src; _Float16* dst; float* nrm;
  if (row < M_ROWS) {
    src = x + (size_t)row * K_DIM; dst = xh + (size_t)row * K_DIM; nrm = x2 + row;
  } else {
    int r = row - M_ROWS;
    src = w + (size_t)r * K_DIM; dst = wh + (size_t)r * K_DIM; nrm = w2 + r;
  }
  float4 v = ((const float4*)src)[lane];           // 64 lanes x 4 = 256
  float s = v.x*v.x + v.y*v.y + v.z*v.z + v.w*v.w;
  #pragma unroll
  for (int off = 32; off > 0; off >>= 1) s += __shfl_down(s, off);
  if (lane == 0) *nrm = s;
  half4v h; h[0]=(_Float16)v.x; h[1]=(_Float16)v.y; h[2]=(_Float16)v.z; h[3]=(_Float16)v.w;
  ((half4v*)dst)[lane] = h;
}

// -------- 128x128xBK64 GEMM, R6 tile economics + T2 swizzle, but split
// over 8 waves (512 thr): per-wave 64x32 sub-tile -> acc[4][2]=32 VGPR,
// natural live set ~110 < 128 -> __launch_bounds__(512,4) = 2 blocks/CU
// = 16 waves/CU with NO spill (R9's (256,4) forced a ~160->128 spill).
// MODE 0: per-row exp-sum partials.  MODE 1: write normalized softmax.
template <int MODE>
__global__ __launch_bounds__(512, 4) void gemm_pass(
    const _Float16* __restrict__ A, const _Float16* __restrict__ Bm,
    const float* __restrict__ x2g, const float* __restrict__ w2g,
    const float* __restrict__ invg,
    float* __restrict__ partials,
    float* __restrict__ out) {
  __shared__ _Float16 As[128 * 64];   // 16KB, swizzled contents
  __shared__ _Float16 Bs[128 * 64];   // 16KB
  __shared__ float x2s[128];
  __shared__ float w2s[128];
  __shared__ float invs[128];
  __shared__ float rowpart[4][128];   // per-wc partial row sums (MODE 0)

  // XCD partition: xcd = id&7 owns 16 contiguous col-tiles (w slice 1MB, L2-resident);
  // within an XCD, col-tile varies fastest -> A-tile reused 16x consecutively.
  int id   = blockIdx.x;            // grid = 64 row-tiles * 128 col-tiles = 8192
  int xcd  = id & 7;
  int rest = id >> 3;               // 0..1023
  int ct   = xcd * 16 + (rest & 15);
  int rt   = rest >> 4;             // 0..63
  int brow = rt * 128;
  int bcol = ct * 128;

  int tid = threadIdx.x, lane = tid & 63, wid = tid >> 6;
  int wr = wid >> 2, wc = wid & 3;  // 2x4 waves, each 64x32 output

  if (tid < 128) {
    x2s[tid] = x2g[brow + tid];
    if (MODE == 1) invs[tid] = invg[brow + tid];
  } else if (tid < 256) {
    w2s[tid - 128] = w2g[bcol + tid - 128];
  }

  vf4 acc[4][2] = {};

  for (int kk = 0; kk < K_DIM; kk += 64) {
    // stage: seg = 8 rows of [row][64] fp16 (1KB); 16 segs/matrix, 2/wave.
    // LDS dest linear (base + lane*16); global source column pre-swizzled:
    // LDS[row][cb] = global[row][cb ^ ((row&7)<<4)]  (involution).
    #pragma unroll
    for (int i = 0; i < 2; ++i) {
      int seg = wid * 2 + i;
      int r   = seg * 8 + (lane >> 3);
      int colhalf = ((lane & 7) * 8) ^ ((lane >> 3) << 3);   // fp16 elems
      gload16(A  + (size_t)(brow + r) * K_DIM + kk + colhalf, (char*)As + seg * 1024);
      gload16(Bm + (size_t)(bcol + r) * K_DIM + kk + colhalf, (char*)Bs + seg * 1024);
    }
    __syncthreads();   // compiler drains vmcnt(0) before s_barrier

    #pragma unroll
    for (int ks = 0; ks < 2; ++ks) {          // two K=32 MFMA steps per BK=64
      half8 af[4], bf[2];
      int cb = ks * 64 + (lane >> 4) * 16;    // column byte within 128B row
      #pragma unroll
      for (int m = 0; m < 4; ++m) {
        int ra = wr * 64 + m * 16 + (lane & 15);
        af[m] = *(const half8*)((const char*)As + ra * 128 + (cb ^ ((ra & 7) << 4)));
      }
      #pragma unroll
      for (int n = 0; n < 2; ++n) {
        int rb = wc * 32 + n * 16 + (lane & 15);
        bf[n] = *(const half8*)((const char*)Bs + rb * 128 + (cb ^ ((rb & 7) << 4)));
      }
      #pragma unroll
      for (int m = 0; m < 4; ++m)
        #pragma unroll
        for (int n = 0; n < 2; ++n)
          acc[m][n] = __builtin_amdgcn_mfma_f32_16x16x32_f16(af[m], bf[n], acc[m][n], 0, 0, 0);
    }
    __syncthreads();
  }

  if (MODE == 0) {
    // epilogue: per-row sums of exp(-2*dist) over this tile's 128 cols
    #pragma unroll
    for (int m = 0; m < 4; ++m) {
      #pragma unroll
      for (int j = 0; j < 4; ++j) {
        int rl = wr * 64 + m * 16 + ((lane >> 4) << 2) + j;   // C/D: row=(lane>>4)*4+j
        float x2v = x2s[rl];
        float sm = 0.f;
        #pragma unroll
        for (int n = 0; n < 2; ++n) {
          int cl = wc * 32 + n * 16 + (lane & 15);            // C/D: col=lane&15
          float d2 = fmaxf(x2v + w2s[cl] - 2.0f * acc[m][n][j], 0.0f);
          sm += __expf(-2.0f * sqrtf(d2));
        }
        // reduce across the 16 lanes (lane&15) sharing this row
        sm += __shfl_xor(sm, 1);
        sm += __shfl_xor(sm, 2);
        sm += __shfl_xor(sm, 4);
        sm += __shfl_xor(sm, 8);
        if ((lane & 15) == 0) rowpart[wc][rl] = sm;   // rl disjoint across wr
      }
    }
    __syncthreads();
    if (tid < 128)
      partials[(size_t)(brow + tid) * NTILE + ct] =
          rowpart[0][tid] + rowpart[1][tid] + rowpart[2][tid] + rowpart[3][tid];
  } else {
    // epilogue: out = exp(-2*dist) * inv_rowsum
    #pragma unroll
    for (int m = 0; m < 4; ++m) {
      #pragma unroll
      for (int j = 0; j < 4; ++j) {
        int rl = wr * 64 + m * 16 + ((lane >> 4) << 2) + j;
        float x2v = x2s[rl];
        float inv = invs[rl];
        size_t rowbase = (size_t)(brow + rl) * N_COLS + bcol;
        #pragma unroll
        for (int n = 0; n < 2; ++n) {
          int cl = wc * 32 + n * 16 + (lane & 15);
          float d2 = fmaxf(x2v + w2s[cl] - 2.0f * acc[m][n][j], 0.0f);
          out[rowbase + cl] = __expf(-2.0f * sqrtf(d2)) * inv;
        }
      }
    }
  }
}

// ------------- reduce partials -> 1/rowsum, one wave per row -----------
__global__ __launch_bounds__(256) void reduce_inv(
    const float* __restrict__ partials, float* __restrict__ invg) {
  int row  = blockIdx.x * 4 + (threadIdx.x >> 6);
  int lane = threadIdx.x & 63;
  const float* p = partials + (size_t)row * NTILE;
  float s = p[lane] + p[lane + 64];   // NTILE == 128
  #pragma unroll
  for (int off = 32; off > 0; off >>= 1) s += __shfl_down(s, off);
  if (lane == 0) invg[row] = 1.0f / s;
}

// =============== fallback path (ws tiny): logits + row softmax ===============
__global__ __launch_bounds__(256, 2) void gemm_logit_f32(
    const float* __restrict__ xf, const float* __restrict__ wf,
    float* __restrict__ out, int mbase) {
  __shared__ _Float16 As[128 * 64];
  __shared__ _Float16 Bs[128 * 64];
  __shared__ float x2s[128];
  __shared__ float w2s[128];

  int id  = blockIdx.x;
  int xcd = id & 7;
  int rt  = (id >> 3) & 15;
  int c2  = id >> 7;
  int brow = mbase + rt * 128;
  int bcol = (xcd * 16 + c2) * 128;

  int tid = threadIdx.x, lane = tid & 63, wid = tid >> 6;
  int wr = wid >> 1, wc = wid & 1;

  vf4 acc[4][4] = {};

  {
    const float* src = (tid < 128) ? xf + (size_t)(brow + tid) * K_DIM
                                   : wf + (size_t)(bcol + tid - 128) * K_DIM;
    float s = 0.f;
    for (int i = 0; i < 64; ++i) {
      float4 v = ((const float4*)src)[i];
      s += v.x*v.x + v.y*v.y + v.z*v.z + v.w*v.w;
    }
    if (tid < 128) x2s[tid] = s; else w2s[tid - 128] = s;
  }

  for (int kk = 0; kk < K_DIM; kk += 64) {
    #pragma unroll
    for (int i = 0; i < 8; ++i) {
      int idx = i * 256 + tid;
      int r = idx >> 4, kq = idx & 15;
      float4 va = ((const float4*)(xf + (size_t)(brow + r) * K_DIM + kk))[kq];
      float4 vb = ((const float4*)(wf + (size_t)(bcol + r) * K_DIM + kk))[kq];
      half4v ha; ha[0]=(_Float16)va.x; ha[1]=(_Float16)va.y; ha[2]=(_Float16)va.z; ha[3]=(_Float16)va.w;
      half4v hb; hb[0]=(_Float16)vb.x; hb[1]=(_Float16)vb.y; hb[2]=(_Float16)vb.z; hb[3]=(_Float16)vb.w;
      *(half4v*)&As[r * 64 + kq * 4] = ha;
      *(half4v*)&Bs[r * 64 + kq * 4] = hb;
    }
    __syncthreads();
    #pragma unroll
    for (int ks = 0; ks < 2; ++ks) {
      half8 af[4], bf[4];
      #pragma unroll
      for (int m = 0; m < 4; ++m)
        af[m] = *(const half8*)&As[(wr*64 + m*16 + (lane & 15)) * 64 + ks*32 + (lane >> 4) * 8];
      #pragma unroll
      for (int n = 0; n < 4; ++n)
        bf[n] = *(const half8*)&Bs[(wc*64 + n*16 + (lane & 15)) * 64 + ks*32 + (lane >> 4) * 8];
      #pragma unroll
      for (int m = 0; m < 4; ++m)
        #pragma unroll
        for (int n = 0; n < 4; ++n)
          acc[m][n] = __builtin_amdgcn_mfma_f32_16x16x32_f16(af[m], bf[n], acc[m][n], 0, 0, 0);
    }
    __syncthreads();
  }

  #pragma unroll
  for (int m = 0; m < 4; ++m) {
    int rl = wr * 64 + m * 16 + ((lane >> 4) << 2);
    #pragma unroll
    for (int n = 0; n < 4; ++n) {
      int cl = wc * 64 + n * 16 + (lane & 15);
      int c  = bcol + cl;
      float w2v = w2s[cl];
      #pragma unroll
      for (int j = 0; j < 4; ++j) {
        int r = brow + rl + j;
        float d2 = fmaxf(x2s[rl + j] + w2v - 2.0f * acc[m][n][j], 0.0f);
        out[(size_t)r * N_COLS + c] = -2.0f * sqrtf(d2);
      }
    }
  }
}

__global__ __launch_bounds__(256) void softmax_norm(float* __restrict__ io, int mbase) {
  int row = mbase + blockIdx.x;
  float* p = io + (size_t)row * N_COLS;
  int tid = threadIdx.x;
  __shared__ float wsum[4];

  float4 v[16];
  float s = 0.f;
  #pragma unroll
  for (int i = 0; i < 16; ++i) {
    v[i] = ((const float4*)p)[i * 256 + tid];
    v[i].x = __expf(v[i].x); v[i].y = __expf(v[i].y);
    v[i].z = __expf(v[i].z); v[i].w = __expf(v[i].w);
    s += v[i].x + v[i].y + v[i].z + v[i].w;
  }
  #pragma unroll
  for (int off = 32; off > 0; off >>= 1) s += __shfl_down(s, off);
  if ((tid & 63) == 0) wsum[tid >> 6] = s;
  __syncthreads();
  float inv = 1.0f / (wsum[0] + wsum[1] + wsum[2] + wsum[3]);
  #pragma unroll
  for (int i = 0; i < 16; ++i) {
    float4 o = v[i];
    o.x *= inv; o.y *= inv; o.z *= inv; o.w *= inv;
    ((float4*)p)[i * 256 + tid] = o;
  }
}

extern "C" void kernel_launch(void* const* d_in, const int* in_sizes, int n_in,
                              void* d_out, int out_size, void* d_ws, size_t ws_size,
                              hipStream_t stream) {
  const float* x = (const float*)d_in[0];
  const float* w = (const float*)d_in[1];
  float* out = (float*)d_out;

  // ws layout: x2[8192] | w2[16384] | invsum[8192] | partials[8192*128] |
  //            xh fp16 [8192*256] | wh fp16 [16384*256]
  char* ws = (char*)d_ws;
  float* x2 = (float*)ws;
  float* w2 = x2 + M_ROWS;
  float* invsum = w2 + N_COLS;
  float* partials = invsum + M_ROWS;
  _Float16* xh = (_Float16*)(partials + (size_t)M_ROWS * NTILE);
  _Float16* wh = xh + (size_t)M_ROWS * K_DIM;
  const size_t need = ((size_t)(M_ROWS + N_COLS + M_ROWS) + (size_t)M_ROWS * NTILE) * 4
                    + (size_t)(M_ROWS + N_COLS) * K_DIM * 2;

  if (ws_size >= need) {
    prep_kernel<<<(M_ROWS + N_COLS) / 4, 256, 0, stream>>>(x, w, x2, w2, xh, wh);
    gemm_pass<0><<<(M_ROWS / 128) * (N_COLS / 128), 512, 0, stream>>>(
        xh, wh, x2, w2, nullptr, partials, nullptr);
    reduce_inv<<<M_ROWS / 4, 256, 0, stream>>>(partials, invsum);
    gemm_pass<1><<<(M_ROWS / 128) * (N_COLS / 128), 512, 0, stream>>>(
        xh, wh, x2, w2, invsum, nullptr, out);
  } else {
    for (int c = 0; c < NCHUNK; ++c) {
      int mbase = c * CHUNK;
      gemm_logit_f32<<<(CHUNK / 128) * (N_COLS / 128), 256, 0, stream>>>(
          x, w, out, mbase);
      softmax_norm<<<CHUNK, 256, 0, stream>>>(out, mbase);
    }
  }
}